// Round 1
// baseline (597.778 us; speedup 1.0000x reference)
//
#include <hip/hip_runtime.h>
#include <hip/hip_bf16.h>

#define BT    8192
#define TOBS  50
#define SDEC  100
#define HID   128
#define NG    512
#define EMB   64
#define MD    256
#define M2N   112
#define NZ    16
#define ROWS  32
#define KPAD  136    // padded LDS row stride (bf16 elems): 272B, 68 dwords = 4 mod 32 banks
#define H1PAD 264

using bf16x8 = __attribute__((ext_vector_type(8))) short;
using f32x4  = __attribute__((ext_vector_type(4))) float;

struct alignas(16) SMem {
  union {
    unsigned short whh[NG * KPAD];       // staged Whh bf16 [512][136] (136 KB)
    unsigned short h1[ROWS * H1PAD];     // MLP hidden [32][264] (reuse between phases)
  } w;
  unsigned short h[2][ROWS * KPAD];      // h double buffer [32][136] bf16
  float offl[2][ROWS][2];                // per-step 2-dim input (fp32, double buffered)
  float part[ROWS][4];                   // decoder readout partials [row][jh*2+p]
};

__device__ __forceinline__ unsigned short f2bf(float x){
  unsigned int u = __builtin_bit_cast(unsigned int, x);
  u += 0x7fffu + ((u >> 16) & 1u);       // RNE
  return (unsigned short)(u >> 16);
}
__device__ __forceinline__ float fsig(float x){
  return __builtin_amdgcn_rcpf(1.0f + __expf(-x));
}
__device__ __forceinline__ float ftanh(float x){
  return 2.0f * __builtin_amdgcn_rcpf(1.0f + __expf(-2.0f * x)) - 1.0f;
}
__device__ __forceinline__ bf16x8 pack8(const float* p){
  float4 a = *(const float4*)p;
  float4 b = *(const float4*)(p + 4);
  bf16x8 r;
  r[0]=(short)f2bf(a.x); r[1]=(short)f2bf(a.y); r[2]=(short)f2bf(a.z); r[3]=(short)f2bf(a.w);
  r[4]=(short)f2bf(b.x); r[5]=(short)f2bf(b.y); r[6]=(short)f2bf(b.z); r[7]=(short)f2bf(b.w);
  return r;
}

extern "C" __global__ void __launch_bounds__(256, 1)
seqgen(const float* __restrict__ obs,
       const float* __restrict__ We,    const float* __restrict__ be,
       const float* __restrict__ Wih_e, const float* __restrict__ Whh_e, const float* __restrict__ b_e,
       const float* __restrict__ Wm1,   const float* __restrict__ bm1,
       const float* __restrict__ Wm2,   const float* __restrict__ bm2,
       const float* __restrict__ Wd,    const float* __restrict__ bd,
       const float* __restrict__ Wih_d, const float* __restrict__ Whh_d, const float* __restrict__ b_d,
       const float* __restrict__ Wr,    const float* __restrict__ br,
       const float* __restrict__ z,     float* __restrict__ out)
{
  __shared__ SMem sm;
  const int tid  = threadIdx.x;
  const int lane = tid & 63;
  const int wv   = tid >> 6;       // wave 0..3
  const int rg   = wv >> 1;        // row group 0..1 (16 rows each)
  const int jh   = wv & 1;         // j-half 0..1 (64 hidden units each)
  const int cc   = lane & 15;
  const int qd   = lane >> 4;
  const int R0   = blockIdx.x * ROWS;
  const int rowA = rg * 16 + cc;         // A-operand row (m = lane&15)
  const int rowC0= rg * 16 + qd * 4;     // C/D row base (row = quad*4 + reg)

  // ---------- stage encoder Whh -> LDS bf16 ----------
  for (int i = tid; i < NG * HID / 4; i += 256){
    int n = i >> 5;
    int k = (i & 31) * 4;
    float4 v = *(const float4*)(Whh_e + n * HID + k);
    unsigned short* d = &sm.w.whh[n * KPAD + k];
    d[0]=f2bf(v.x); d[1]=f2bf(v.y); d[2]=f2bf(v.z); d[3]=f2bf(v.w);
  }
  // ---------- fused input consts: {b', w0, w1} per gate row (into h[1] region) ----------
  {
    float4* cl = (float4*)&sm.h[1][0];
    for (int n = tid * 2; n < tid * 2 + 2; ++n){
      const float* wr = Wih_e + n * EMB;
      float w0 = 0.f, w1 = 0.f, bb = b_e[n];
      for (int e = 0; e < EMB; ++e){
        float w = wr[e];
        w0 += w * We[e*2+0]; w1 += w * We[e*2+1]; bb += w * be[e];
      }
      cl[n] = make_float4(bb, w0, w1, 0.f);
    }
  }
  // ---------- zero h[0] ----------
  for (int i = tid; i < ROWS * KPAD / 2; i += 256)
    ((unsigned int*)&sm.h[0][0])[i] = 0u;
  // ---------- producers: first offset = obs[:,0] ----------
  float obscur = 0.f, offcur = 0.f;
  const int prow = tid >> 1, pp = tid & 1;
  if (tid < 64){
    obscur = obs[(size_t)(R0 + prow) * (TOBS*2) + pp];
    offcur = obscur;
    sm.offl[0][prow][pp] = offcur;
  }
  __syncthreads();

  float bc[16], w0c[16], w1c[16];
  {
    const float4* cl = (const float4*)&sm.h[1][0];
    #pragma unroll
    for (int g = 0; g < 4; ++g)
      #pragma unroll
      for (int t = 0; t < 4; ++t){
        float4 v = cl[g*128 + jh*64 + t*16 + cc];
        bc[g*4+t] = v.x; w0c[g*4+t] = v.y; w1c[g*4+t] = v.z;
      }
  }
  __syncthreads();   // everyone done reading consts before step0 overwrites h[1]

  float cst[16];
  #pragma unroll
  for (int i = 0; i < 16; ++i) cst[i] = 0.f;

  // ================= encoder: 50 steps =================
  for (int t = 0; t < TOBS; ++t){
    const int par = t & 1;
    float o0[4], o1[4];
    #pragma unroll
    for (int r = 0; r < 4; ++r){
      o0[r] = sm.offl[par][rowC0 + r][0];
      o1[r] = sm.offl[par][rowC0 + r][1];
    }
    // prefetch next obs early (hidden behind MFMA)
    float nx = 0.f;
    if (tid < 64 && t < TOBS - 1)
      nx = obs[(size_t)(R0 + prow) * (TOBS*2) + (t+1)*2 + pp];

    f32x4 acc[16];
    #pragma unroll
    for (int ti = 0; ti < 16; ++ti)
      #pragma unroll
      for (int r = 0; r < 4; ++r)
        acc[ti][r] = bc[ti] + w0c[ti]*o0[r] + w1c[ti]*o1[r];

    bf16x8 af[4];
    #pragma unroll
    for (int kt = 0; kt < 4; ++kt)
      af[kt] = *(const bf16x8*)&sm.h[par][rowA * KPAD + kt*32 + qd*8];

    #pragma unroll
    for (int g = 0; g < 4; ++g)
      #pragma unroll
      for (int tt = 0; tt < 4; ++tt){
        const int ti = g*4 + tt;
        const unsigned short* wb = &sm.w.whh[(g*128 + jh*64 + tt*16 + cc) * KPAD + qd*8];
        #pragma unroll
        for (int kt = 0; kt < 4; ++kt)
          acc[ti] = __builtin_amdgcn_mfma_f32_16x16x32_bf16(
                      af[kt], *(const bf16x8*)(wb + kt*32), acc[ti], 0, 0, 0);
      }

    unsigned short* hn = &sm.h[par ^ 1][0];
    #pragma unroll
    for (int tt = 0; tt < 4; ++tt)
      #pragma unroll
      for (int r = 0; r < 4; ++r){
        float iv = acc[0*4+tt][r], fv = acc[1*4+tt][r];
        float gv = acc[2*4+tt][r], ov = acc[3*4+tt][r];
        float cn = fsig(fv) * cst[tt*4+r] + fsig(iv) * ftanh(gv);
        cst[tt*4+r] = cn;
        float hh = fsig(ov) * ftanh(cn);
        hn[(rowC0 + r) * KPAD + jh*64 + tt*16 + cc] = f2bf(hh);
      }
    if (tid < 64){
      if (t < TOBS - 1){ offcur = nx - obscur; obscur = nx; }
      sm.offl[par ^ 1][prow][pp] = offcur;   // t=49 rewrites same off -> decoder input
    }
    __syncthreads();
  }
  // hF now in sm.h[0]

  // ================= MLP =================
  {
    if (tid < 64) sm.part[prow][pp] = obscur;   // obs[:,T-1] = cumsum base
    bf16x8 af[4];
    #pragma unroll
    for (int kt = 0; kt < 4; ++kt)
      af[kt] = *(const bf16x8*)&sm.h[0][rowA * KPAD + kt*32 + qd*8];
    f32x4 a1[8];
    #pragma unroll
    for (int t2 = 0; t2 < 8; ++t2){
      const int n = jh*128 + t2*16 + cc;
      float b = bm1[n];
      f32x4 a; a[0]=b; a[1]=b; a[2]=b; a[3]=b;
      const float* wrow = Wm1 + n * HID;
      #pragma unroll
      for (int kt = 0; kt < 4; ++kt)
        a = __builtin_amdgcn_mfma_f32_16x16x32_bf16(af[kt], pack8(wrow + kt*32 + qd*8), a, 0,0,0);
      a1[t2] = a;
    }
    __syncthreads();   // all h[0]/whh reads done; whh region reusable as h1
    #pragma unroll
    for (int t2 = 0; t2 < 8; ++t2)
      #pragma unroll
      for (int r = 0; r < 4; ++r){
        float v = a1[t2][r]; v = v > 0.f ? v : 0.f;
        sm.w.h1[(rowC0 + r) * H1PAD + jh*128 + t2*16 + cc] = f2bf(v);
      }
    __syncthreads();
    bf16x8 af2[8];
    #pragma unroll
    for (int kt = 0; kt < 8; ++kt)
      af2[kt] = *(const bf16x8*)&sm.w.h1[rowA * H1PAD + kt*32 + qd*8];
    f32x4 a2[4];
    #pragma unroll
    for (int tt = 0; tt < 4; ++tt){
      if (jh*64 + tt*16 >= M2N) continue;
      const int v = jh*64 + tt*16 + cc;
      float b = bm2[v];
      f32x4 a; a[0]=b; a[1]=b; a[2]=b; a[3]=b;
      const float* wrow = Wm2 + v * MD;
      #pragma unroll
      for (int kt = 0; kt < 8; ++kt)
        a = __builtin_amdgcn_mfma_f32_16x16x32_bf16(af2[kt], pack8(wrow + kt*32 + qd*8), a, 0,0,0);
      a2[tt] = a;
    }
    __syncthreads();
    #pragma unroll
    for (int tt = 0; tt < 4; ++tt){
      if (jh*64 + tt*16 >= M2N) continue;
      #pragma unroll
      for (int r = 0; r < 4; ++r){
        float vv = a2[tt][r]; vv = vv > 0.f ? vv : 0.f;
        sm.h[0][(rowC0 + r) * KPAD + jh*64 + tt*16 + cc] = f2bf(vv);
      }
    }
    for (int i = tid; i < ROWS * NZ; i += 256){
      int row = i >> 4, nz = i & 15;
      sm.h[0][row * KPAD + M2N + nz] = f2bf(z[(size_t)(R0 + row) * NZ + nz]);
    }
  }

  // ================= decoder prep =================
  __syncthreads();   // h1 reads complete before overwriting with Whh_d
  for (int i = tid; i < NG * HID / 4; i += 256){
    int n = i >> 5;
    int k = (i & 31) * 4;
    float4 v = *(const float4*)(Whh_d + n * HID + k);
    unsigned short* d = &sm.w.whh[n * KPAD + k];
    d[0]=f2bf(v.x); d[1]=f2bf(v.y); d[2]=f2bf(v.z); d[3]=f2bf(v.w);
  }
  {
    float4* cl = (float4*)&sm.h[1][0];
    for (int n = tid * 2; n < tid * 2 + 2; ++n){
      const float* wr = Wih_d + n * EMB;
      float w0 = 0.f, w1 = 0.f, bb = b_d[n];
      for (int e = 0; e < EMB; ++e){
        float w = wr[e];
        w0 += w * Wd[e*2+0]; w1 += w * Wd[e*2+1]; bb += w * bd[e];
      }
      cl[n] = make_float4(bb, w0, w1, 0.f);
    }
  }
  __syncthreads();
  {
    const float4* cl = (const float4*)&sm.h[1][0];
    #pragma unroll
    for (int g = 0; g < 4; ++g)
      #pragma unroll
      for (int t = 0; t < 4; ++t){
        float4 v = cl[g*128 + jh*64 + t*16 + cc];
        bc[g*4+t] = v.x; w0c[g*4+t] = v.y; w1c[g*4+t] = v.z;
      }
  }
  float wr0[4], wr1[4];
  #pragma unroll
  for (int t = 0; t < 4; ++t){
    wr0[t] = Wr[jh*64 + t*16 + cc];
    wr1[t] = Wr[HID + jh*64 + t*16 + cc];
  }
  const float br0 = br[0], br1 = br[1];
  float cum0 = 0.f, cum1 = 0.f, pc0 = 0.f, pc1 = 0.f;
  if (tid < 32){ cum0 = sm.part[tid][0]; cum1 = sm.part[tid][1]; }
  #pragma unroll
  for (int i = 0; i < 16; ++i) cst[i] = 0.f;
  __syncthreads();

  // ================= decoder: 100 steps =================
  for (int s = 0; s < SDEC; ++s){
    const int par = s & 1;
    float o0[4], o1[4];
    #pragma unroll
    for (int r = 0; r < 4; ++r){
      o0[r] = sm.offl[par][rowC0 + r][0];
      o1[r] = sm.offl[par][rowC0 + r][1];
    }
    f32x4 acc[16];
    #pragma unroll
    for (int ti = 0; ti < 16; ++ti)
      #pragma unroll
      for (int r = 0; r < 4; ++r)
        acc[ti][r] = bc[ti] + w0c[ti]*o0[r] + w1c[ti]*o1[r];

    bf16x8 af[4];
    #pragma unroll
    for (int kt = 0; kt < 4; ++kt)
      af[kt] = *(const bf16x8*)&sm.h[par][rowA * KPAD + kt*32 + qd*8];

    #pragma unroll
    for (int g = 0; g < 4; ++g)
      #pragma unroll
      for (int tt = 0; tt < 4; ++tt){
        const int ti = g*4 + tt;
        const unsigned short* wb = &sm.w.whh[(g*128 + jh*64 + tt*16 + cc) * KPAD + qd*8];
        #pragma unroll
        for (int kt = 0; kt < 4; ++kt)
          acc[ti] = __builtin_amdgcn_mfma_f32_16x16x32_bf16(
                      af[kt], *(const bf16x8*)(wb + kt*32), acc[ti], 0, 0, 0);
      }

    unsigned short* hn = &sm.h[par ^ 1][0];
    float pr0[4] = {0.f,0.f,0.f,0.f}, pr1[4] = {0.f,0.f,0.f,0.f};
    #pragma unroll
    for (int tt = 0; tt < 4; ++tt)
      #pragma unroll
      for (int r = 0; r < 4; ++r){
        float iv = acc[0*4+tt][r], fv = acc[1*4+tt][r];
        float gv = acc[2*4+tt][r], ov = acc[3*4+tt][r];
        float cn = fsig(fv) * cst[tt*4+r] + fsig(iv) * ftanh(gv);
        cst[tt*4+r] = cn;
        float hh = fsig(ov) * ftanh(cn);
        hn[(rowC0 + r) * KPAD + jh*64 + tt*16 + cc] = f2bf(hh);
        pr0[r] += wr0[tt] * hh;
        pr1[r] += wr1[tt] * hh;
      }
    // reduce readout over the 16 lanes of each quad (cc bits)
    #pragma unroll
    for (int m = 1; m < 16; m <<= 1)
      #pragma unroll
      for (int r = 0; r < 4; ++r){
        pr0[r] += __shfl_xor(pr0[r], m, 64);
        pr1[r] += __shfl_xor(pr1[r], m, 64);
      }
    if (cc == 0){
      #pragma unroll
      for (int r = 0; r < 4; ++r){
        float2 v; v.x = pr0[r]; v.y = pr1[r];
        *(float2*)&sm.part[rowC0 + r][jh*2] = v;
      }
    }
    __syncthreads();
    if (tid < 32){
      float4 p4 = *(const float4*)&sm.part[tid][0];
      float of0 = p4.x + p4.z + br0;
      float of1 = p4.y + p4.w + br1;
      cum0 += of0; cum1 += of1;
      if (s & 1){
        float4 st; st.x = pc0; st.y = pc1; st.z = cum0; st.w = cum1;
        *(float4*)(out + ((size_t)(R0 + tid) * SDEC + (s-1)) * 2) = st;
      } else { pc0 = cum0; pc1 = cum1; }
      sm.offl[par ^ 1][tid][0] = of0;
      sm.offl[par ^ 1][tid][1] = of1;
    }
    __syncthreads();
  }
}

extern "C" void kernel_launch(void* const* d_in, const int* in_sizes, int n_in,
                              void* d_out, int out_size, void* d_ws, size_t ws_size,
                              hipStream_t stream) {
  (void)in_sizes; (void)n_in; (void)d_ws; (void)ws_size; (void)out_size;
  const float* obs   = (const float*)d_in[0];
  // d_in[1] = num_steps (100), compile-time constant here
  const float* We    = (const float*)d_in[2];
  const float* be    = (const float*)d_in[3];
  const float* Wih_e = (const float*)d_in[4];
  const float* Whh_e = (const float*)d_in[5];
  const float* b_e   = (const float*)d_in[6];
  const float* Wm1   = (const float*)d_in[7];
  const float* bm1   = (const float*)d_in[8];
  const float* Wm2   = (const float*)d_in[9];
  const float* bm2   = (const float*)d_in[10];
  const float* Wd    = (const float*)d_in[11];
  const float* bd    = (const float*)d_in[12];
  const float* Wih_d = (const float*)d_in[13];
  const float* Whh_d = (const float*)d_in[14];
  const float* b_d   = (const float*)d_in[15];
  const float* Wr    = (const float*)d_in[16];
  const float* br    = (const float*)d_in[17];
  const float* zz    = (const float*)d_in[18];
  hipLaunchKernelGGL(seqgen, dim3(BT / ROWS), dim3(256), 0, stream,
                     obs, We, be, Wih_e, Whh_e, b_e, Wm1, bm1, Wm2, bm2,
                     Wd, bd, Wih_d, Whh_d, b_d, Wr, br, zz, (float*)d_out);
}

// Round 2
// 407.259 us; speedup vs baseline: 1.4678x; 1.4678x over previous
//
#include <hip/hip_runtime.h>

#define TOBS  50
#define SDEC  100
#define HID   128
#define NG    512
#define EMB   64
#define MD    256
#define M2N   112
#define NZ    16
#define ROWS  32
#define KPAD  140    // shorts; 70 dwords = 6 mod 32 -> conflict-free-ish rows
#define H1PAD 268    // shorts; 134 dwords = 6 mod 32

using bf16x8 = __attribute__((ext_vector_type(8))) short;
using f32x4  = __attribute__((ext_vector_type(4))) float;

struct alignas(16) SMem {
  unsigned short h[2][ROWS * KPAD];          // 17920 B  h double buffer (bf16)
  float offs[TOBS][ROWS][2];                 // 12800 B  encoder inputs (fp32)
  union {
    unsigned short h1[ROWS * H1PAD];         // 17152 B  MLP hidden
    float4 cl[NG];                           //  8192 B  fused input consts staging
  } u;
  float delta[ROWS][2];                      //   256 B  decoder step-0 correction
};

__device__ __forceinline__ unsigned short f2bf(float x){
  unsigned int u = __builtin_bit_cast(unsigned int, x);
  u += 0x7fffu + ((u >> 16) & 1u);           // RNE
  return (unsigned short)(u >> 16);
}
__device__ __forceinline__ float bf2f(unsigned short u){
  return __builtin_bit_cast(float, (unsigned int)u << 16);
}
__device__ __forceinline__ float fsig(float x){
  return __builtin_amdgcn_rcpf(1.0f + __expf(-x));
}
__device__ __forceinline__ float ftanh(float x){
  return 2.0f * __builtin_amdgcn_rcpf(1.0f + __expf(-2.0f * x)) - 1.0f;
}
__device__ __forceinline__ bf16x8 pack8(const float* p){
  float4 a = *(const float4*)p;
  float4 b = *(const float4*)(p + 4);
  bf16x8 r;
  r[0]=(short)f2bf(a.x); r[1]=(short)f2bf(a.y); r[2]=(short)f2bf(a.z); r[3]=(short)f2bf(a.w);
  r[4]=(short)f2bf(b.x); r[5]=(short)f2bf(b.y); r[6]=(short)f2bf(b.z); r[7]=(short)f2bf(b.w);
  return r;
}

extern "C" __global__ void __launch_bounds__(512, 2)
seqgen(const float* __restrict__ obs,
       const float* __restrict__ We,    const float* __restrict__ be,
       const float* __restrict__ Wih_e, const float* __restrict__ Whh_e, const float* __restrict__ b_e,
       const float* __restrict__ Wm1,   const float* __restrict__ bm1,
       const float* __restrict__ Wm2,   const float* __restrict__ bm2,
       const float* __restrict__ Wd,    const float* __restrict__ bd,
       const float* __restrict__ Wih_d, const float* __restrict__ Whh_d, const float* __restrict__ b_d,
       const float* __restrict__ Wr,    const float* __restrict__ br,
       const float* __restrict__ z,     float* __restrict__ out)
{
  __shared__ SMem sm;
  const int tid  = threadIdx.x;
  const int lane = tid & 63;
  const int jq   = tid >> 6;          // wave id = hidden column tile (0..7)
  const int cc   = lane & 15;
  const int qd   = lane >> 4;
  const int R0   = blockIdx.x * ROWS;
  const int colj = jq * 16 + cc;      // this lane's hidden column

  // ---------------- prep: offsets -> LDS ----------------
  for (int i = tid; i < TOBS * ROWS * 2; i += 512){
    int t = i >> 6, rp = i & 63, row = rp >> 1, p = rp & 1;
    const float* ob = obs + (size_t)(R0 + row) * (TOBS * 2) + t * 2 + p;
    float v = ob[0];
    if (t) v -= ob[-2];
    sm.offs[t][row][p] = v;
  }
  // zero h[0] (initial encoder state)
  for (int i = tid; i < ROWS * KPAD / 2; i += 512)
    ((unsigned int*)&sm.h[0][0])[i] = 0u;
  // fused input consts per gate row: {b', w0, w1} (rank-2 input path)
  {
    const float* wr = Wih_e + tid * EMB;
    float w0 = 0.f, w1 = 0.f, bb = b_e[tid];
    for (int e = 0; e < EMB; ++e){
      float w = wr[e];
      w0 += w * We[e*2]; w1 += w * We[e*2+1]; bb += w * be[e];
    }
    sm.u.cl[tid] = make_float4(bb, w0, w1, 0.f);
  }
  __syncthreads();

  float bc[4], w0c[4], w1c[4];
  #pragma unroll
  for (int g = 0; g < 4; ++g){
    float4 v = sm.u.cl[g*128 + colj];
    bc[g] = v.x; w0c[g] = v.y; w1c[g] = v.z;
  }
  // ---------------- stage encoder Whh into REGISTERS ----------------
  bf16x8 bfr[4][4];     // [gate][kt]
  #pragma unroll
  for (int kt = 0; kt < 4; ++kt)
    #pragma unroll
    for (int g = 0; g < 4; ++g)
      bfr[g][kt] = pack8(Whh_e + (size_t)(g*128 + colj) * HID + kt*32 + qd*8);

  float cst[8];
  #pragma unroll
  for (int i = 0; i < 8; ++i) cst[i] = 0.f;

  // ================= encoder: 50 steps, ONE barrier/step =================
  for (int t = 0; t < TOBS; ++t){
    const int par = t & 1;
    float2 o[2][4];
    #pragma unroll
    for (int rg = 0; rg < 2; ++rg)
      #pragma unroll
      for (int r = 0; r < 4; ++r)
        o[rg][r] = *(const float2*)&sm.offs[t][rg*16 + qd*4 + r][0];

    f32x4 acc[4][2];
    #pragma unroll
    for (int g = 0; g < 4; ++g)
      #pragma unroll
      for (int rg = 0; rg < 2; ++rg)
        #pragma unroll
        for (int r = 0; r < 4; ++r)
          acc[g][rg][r] = bc[g] + w0c[g]*o[rg][r].x + w1c[g]*o[rg][r].y;

    bf16x8 af[2][4];
    #pragma unroll
    for (int rg = 0; rg < 2; ++rg)
      #pragma unroll
      for (int kt = 0; kt < 4; ++kt)
        af[rg][kt] = *(const bf16x8*)&sm.h[par][(rg*16 + cc)*KPAD + kt*32 + qd*8];

    #pragma unroll
    for (int kt = 0; kt < 4; ++kt)
      #pragma unroll
      for (int g = 0; g < 4; ++g)
        #pragma unroll
        for (int rg = 0; rg < 2; ++rg)
          acc[g][rg] = __builtin_amdgcn_mfma_f32_16x16x32_bf16(af[rg][kt], bfr[g][kt], acc[g][rg], 0,0,0);

    unsigned short* hn = &sm.h[par ^ 1][0];
    #pragma unroll
    for (int rg = 0; rg < 2; ++rg)
      #pragma unroll
      for (int r = 0; r < 4; ++r){
        const int ci = rg*4 + r;
        float iv = acc[0][rg][r], fv = acc[1][rg][r], gv = acc[2][rg][r], ov = acc[3][rg][r];
        float cn = fsig(fv) * cst[ci] + fsig(iv) * ftanh(gv);
        cst[ci] = cn;
        float hh = fsig(ov) * ftanh(cn);
        hn[(rg*16 + qd*4 + r)*KPAD + colj] = f2bf(hh);
      }
    __syncthreads();
  }
  // hF in sm.h[0]

  // ================= MLP =================
  {
    bf16x8 af[2][4];
    #pragma unroll
    for (int rg = 0; rg < 2; ++rg)
      #pragma unroll
      for (int kt = 0; kt < 4; ++kt)
        af[rg][kt] = *(const bf16x8*)&sm.h[0][(rg*16 + cc)*KPAD + kt*32 + qd*8];
    f32x4 a1[2][2];
    #pragma unroll
    for (int t2 = 0; t2 < 2; ++t2){
      const int n = jq*32 + t2*16 + cc;
      float b = bm1[n];
      #pragma unroll
      for (int rg = 0; rg < 2; ++rg){ a1[t2][rg][0]=b; a1[t2][rg][1]=b; a1[t2][rg][2]=b; a1[t2][rg][3]=b; }
      #pragma unroll
      for (int kt = 0; kt < 4; ++kt){
        bf16x8 bb = pack8(Wm1 + (size_t)n * HID + kt*32 + qd*8);
        #pragma unroll
        for (int rg = 0; rg < 2; ++rg)
          a1[t2][rg] = __builtin_amdgcn_mfma_f32_16x16x32_bf16(af[rg][kt], bb, a1[t2][rg], 0,0,0);
      }
    }
    #pragma unroll
    for (int t2 = 0; t2 < 2; ++t2)
      #pragma unroll
      for (int rg = 0; rg < 2; ++rg)
        #pragma unroll
        for (int r = 0; r < 4; ++r){
          float v = a1[t2][rg][r]; v = v > 0.f ? v : 0.f;
          sm.u.h1[(rg*16 + qd*4 + r)*H1PAD + jq*32 + t2*16 + cc] = f2bf(v);
        }
  }
  __syncthreads();
  {
    bf16x8 af2[2][8];
    #pragma unroll
    for (int rg = 0; rg < 2; ++rg)
      #pragma unroll
      for (int kt = 0; kt < 8; ++kt)
        af2[rg][kt] = *(const bf16x8*)&sm.u.h1[(rg*16 + cc)*H1PAD + kt*32 + qd*8];
    f32x4 a2[2];
    if (jq < 7){
      const int v = jq*16 + cc;
      float b = bm2[v];
      #pragma unroll
      for (int rg = 0; rg < 2; ++rg){ a2[rg][0]=b; a2[rg][1]=b; a2[rg][2]=b; a2[rg][3]=b; }
      #pragma unroll
      for (int kt = 0; kt < 8; ++kt){
        bf16x8 bb = pack8(Wm2 + (size_t)v * MD + kt*32 + qd*8);
        #pragma unroll
        for (int rg = 0; rg < 2; ++rg)
          a2[rg] = __builtin_amdgcn_mfma_f32_16x16x32_bf16(af2[rg][kt], bb, a2[rg], 0,0,0);
      }
    }
    __syncthreads();
    if (jq < 7){
      #pragma unroll
      for (int rg = 0; rg < 2; ++rg)
        #pragma unroll
        for (int r = 0; r < 4; ++r){
          float vv = a2[rg][r]; vv = vv > 0.f ? vv : 0.f;
          sm.h[0][(rg*16 + qd*4 + r)*KPAD + jq*16 + cc] = f2bf(vv);
        }
    }
    for (int i = tid; i < ROWS * NZ; i += 512){
      int row = i >> 4, nz = i & 15;
      sm.h[0][row*KPAD + M2N + nz] = f2bf(z[(size_t)(R0 + row)*NZ + nz]);
    }
  }
  __syncthreads();   // dh complete in h[0]

  // ================= decoder prep =================
  {
    const float* wr = Wih_d + tid * EMB;
    float w0 = 0.f, w1 = 0.f, bb = b_d[tid];
    for (int e = 0; e < EMB; ++e){
      float w = wr[e];
      w0 += w * Wd[e*2]; w1 += w * Wd[e*2+1]; bb += w * bd[e];
    }
    sm.u.cl[tid] = make_float4(bb, w0, w1, 0.f);
  }
  if (tid < 64){   // delta[row][p] = off_last - (Wr.dh + br)
    int row = tid >> 1, p = tid & 1;
    float s = br[p];
    const unsigned short* dh = &sm.h[0][row * KPAD];
    const float* wrp = Wr + p * HID;
    #pragma unroll 8
    for (int j = 0; j < HID; ++j) s += wrp[j] * bf2f(dh[j]);
    sm.delta[row][p] = sm.offs[TOBS-1][row][p] - s;
  }
  __syncthreads();

  const float br0 = br[0], br1 = br[1];
  #pragma unroll
  for (int g = 0; g < 4; ++g){
    float4 v = sm.u.cl[g*128 + colj];
    w0c[g] = v.y; w1c[g] = v.z;
    bc[g] = v.x + v.y*br0 + v.z*br1;     // bc' (feedback-folded bias)
  }
  // stage decoder B' = Whh_d + u0 (x) Wr0 + u1 (x) Wr1, plus readout B5 = Wr rows
  bf16x8 b5[4];
  #pragma unroll
  for (int kt = 0; kt < 4; ++kt){
    const int kb = kt*32 + qd*8;
    float wk0[8], wk1[8];
    *(float4*)&wk0[0] = *(const float4*)(Wr + kb);
    *(float4*)&wk0[4] = *(const float4*)(Wr + kb + 4);
    *(float4*)&wk1[0] = *(const float4*)(Wr + HID + kb);
    *(float4*)&wk1[4] = *(const float4*)(Wr + HID + kb + 4);
    {
      bf16x8 tv;
      #pragma unroll
      for (int j = 0; j < 8; ++j) tv[j] = 0;
      if (cc < 2){
        const float* w = (cc == 0) ? wk0 : wk1;
        #pragma unroll
        for (int j = 0; j < 8; ++j) tv[j] = (short)f2bf(w[j]);
      }
      b5[kt] = tv;
    }
    #pragma unroll
    for (int g = 0; g < 4; ++g){
      const float* p = Whh_d + (size_t)(g*128 + colj) * HID + kb;
      float4 a = *(const float4*)p, b = *(const float4*)(p + 4);
      float f[8] = {a.x,a.y,a.z,a.w,b.x,b.y,b.z,b.w};
      bf16x8 tv;
      #pragma unroll
      for (int j = 0; j < 8; ++j)
        tv[j] = (short)f2bf(f[j] + w0c[g]*wk0[j] + w1c[g]*wk1[j]);
      bfr[g][kt] = tv;
    }
  }
  const float brc = (cc == 0) ? br0 : br1;
  float cum[2][4];
  #pragma unroll
  for (int rg = 0; rg < 2; ++rg)
    #pragma unroll
    for (int r = 0; r < 4; ++r) cum[rg][r] = 0.f;
  if (jq == 0 && cc < 2){
    #pragma unroll
    for (int rg = 0; rg < 2; ++rg)
      #pragma unroll
      for (int r = 0; r < 4; ++r)
        cum[rg][r] = obs[(size_t)(R0 + rg*16 + qd*4 + r)*(TOBS*2) + (TOBS-1)*2 + cc];
  }
  #pragma unroll
  for (int i = 0; i < 8; ++i) cst[i] = 0.f;

  // ================= decoder: 100 steps, ONE barrier/step =================
  for (int s = 0; s < SDEC; ++s){
    const int par = s & 1;
    f32x4 acc[4][2];
    if (s == 0){
      float2 d[2][4];
      #pragma unroll
      for (int rg = 0; rg < 2; ++rg)
        #pragma unroll
        for (int r = 0; r < 4; ++r)
          d[rg][r] = *(const float2*)&sm.delta[rg*16 + qd*4 + r][0];
      #pragma unroll
      for (int g = 0; g < 4; ++g)
        #pragma unroll
        for (int rg = 0; rg < 2; ++rg)
          #pragma unroll
          for (int r = 0; r < 4; ++r)
            acc[g][rg][r] = bc[g] + w0c[g]*d[rg][r].x + w1c[g]*d[rg][r].y;
    } else {
      #pragma unroll
      for (int g = 0; g < 4; ++g)
        #pragma unroll
        for (int rg = 0; rg < 2; ++rg)
          #pragma unroll
          for (int r = 0; r < 4; ++r)
            acc[g][rg][r] = bc[g];
    }

    bf16x8 af[2][4];
    #pragma unroll
    for (int rg = 0; rg < 2; ++rg)
      #pragma unroll
      for (int kt = 0; kt < 4; ++kt)
        af[rg][kt] = *(const bf16x8*)&sm.h[par][(rg*16 + cc)*KPAD + kt*32 + qd*8];

    #pragma unroll
    for (int kt = 0; kt < 4; ++kt)
      #pragma unroll
      for (int g = 0; g < 4; ++g)
        #pragma unroll
        for (int rg = 0; rg < 2; ++rg)
          acc[g][rg] = __builtin_amdgcn_mfma_f32_16x16x32_bf16(af[rg][kt], bfr[g][kt], acc[g][rg], 0,0,0);

    // readout of h_{s-1} via 2-column MFMA (wave 0 only): off = Wr.h + br
    if (jq == 0 && s > 0){
      f32x4 a5[2];
      #pragma unroll
      for (int rg = 0; rg < 2; ++rg){ a5[rg][0]=brc; a5[rg][1]=brc; a5[rg][2]=brc; a5[rg][3]=brc; }
      #pragma unroll
      for (int kt = 0; kt < 4; ++kt)
        #pragma unroll
        for (int rg = 0; rg < 2; ++rg)
          a5[rg] = __builtin_amdgcn_mfma_f32_16x16x32_bf16(af[rg][kt], b5[kt], a5[rg], 0,0,0);
      if (cc < 2){
        #pragma unroll
        for (int rg = 0; rg < 2; ++rg)
          #pragma unroll
          for (int r = 0; r < 4; ++r){
            cum[rg][r] += a5[rg][r];
            out[((size_t)(R0 + rg*16 + qd*4 + r)*SDEC + (s-1))*2 + cc] = cum[rg][r];
          }
      }
    }

    unsigned short* hn = &sm.h[par ^ 1][0];
    #pragma unroll
    for (int rg = 0; rg < 2; ++rg)
      #pragma unroll
      for (int r = 0; r < 4; ++r){
        const int ci = rg*4 + r;
        float iv = acc[0][rg][r], fv = acc[1][rg][r], gv = acc[2][rg][r], ov = acc[3][rg][r];
        float cn = fsig(fv) * cst[ci] + fsig(iv) * ftanh(gv);
        cst[ci] = cn;
        float hh = fsig(ov) * ftanh(cn);
        hn[(rg*16 + qd*4 + r)*KPAD + colj] = f2bf(hh);
      }
    __syncthreads();
  }

  // epilogue: off_{S-1} from h[SDEC&1] = h[0]
  if (jq == 0){
    bf16x8 af[2][4];
    #pragma unroll
    for (int rg = 0; rg < 2; ++rg)
      #pragma unroll
      for (int kt = 0; kt < 4; ++kt)
        af[rg][kt] = *(const bf16x8*)&sm.h[SDEC & 1][(rg*16 + cc)*KPAD + kt*32 + qd*8];
    f32x4 a5[2];
    #pragma unroll
    for (int rg = 0; rg < 2; ++rg){ a5[rg][0]=brc; a5[rg][1]=brc; a5[rg][2]=brc; a5[rg][3]=brc; }
    #pragma unroll
    for (int kt = 0; kt < 4; ++kt)
      #pragma unroll
      for (int rg = 0; rg < 2; ++rg)
        a5[rg] = __builtin_amdgcn_mfma_f32_16x16x32_bf16(af[rg][kt], b5[kt], a5[rg], 0,0,0);
    if (cc < 2){
      #pragma unroll
      for (int rg = 0; rg < 2; ++rg)
        #pragma unroll
        for (int r = 0; r < 4; ++r){
          cum[rg][r] += a5[rg][r];
          out[((size_t)(R0 + rg*16 + qd*4 + r)*SDEC + (SDEC-1))*2 + cc] = cum[rg][r];
        }
    }
  }
}

extern "C" void kernel_launch(void* const* d_in, const int* in_sizes, int n_in,
                              void* d_out, int out_size, void* d_ws, size_t ws_size,
                              hipStream_t stream) {
  (void)in_sizes; (void)n_in; (void)d_ws; (void)ws_size; (void)out_size;
  const float* obs   = (const float*)d_in[0];
  // d_in[1] = num_steps (100), compile-time constant here
  const float* We    = (const float*)d_in[2];
  const float* be    = (const float*)d_in[3];
  const float* Wih_e = (const float*)d_in[4];
  const float* Whh_e = (const float*)d_in[5];
  const float* b_e   = (const float*)d_in[6];
  const float* Wm1   = (const float*)d_in[7];
  const float* bm1   = (const float*)d_in[8];
  const float* Wm2   = (const float*)d_in[9];
  const float* bm2   = (const float*)d_in[10];
  const float* Wd    = (const float*)d_in[11];
  const float* bd    = (const float*)d_in[12];
  const float* Wih_d = (const float*)d_in[13];
  const float* Whh_d = (const float*)d_in[14];
  const float* b_d   = (const float*)d_in[15];
  const float* Wr    = (const float*)d_in[16];
  const float* br    = (const float*)d_in[17];
  const float* zz    = (const float*)d_in[18];
  hipLaunchKernelGGL(seqgen, dim3(8192 / ROWS), dim3(512), 0, stream,
                     obs, We, be, Wih_e, Whh_e, b_e, Wm1, bm1, Wm2, bm2,
                     Wd, bd, Wih_d, Whh_d, b_d, Wr, br, zz, (float*)d_out);
}